// Round 1
// baseline (193.731 us; speedup 1.0000x reference)
//
#include <hip/hip_runtime.h>
#include <hip/hip_bf16.h>

// Problem constants (fixed by reference): B=512, F=8, D=4, R=32, U=64
#define NB 512
#define NF 8
#define ND 4
#define NR 32
#define NU 64

typedef float f32x4 __attribute__((ext_vector_type(4)));
typedef short s16x8 __attribute__((ext_vector_type(8)));

// fp32 -> bf16 bits, round-to-nearest-even (3 VALU ops; avoids any doubt about
// __float2bfloat16 rounding mode)
__device__ inline unsigned short to_bf16_bits(float f) {
    unsigned int u = __float_as_uint(f);
    unsigned int r = (u + 0x7FFFu + ((u >> 16) & 1u)) >> 16;
    return (unsigned short)r;
}

// ---------------------------------------------------------------------------
// Pre-pass: K[d][i][j][f][u] (fp32) -> K2[u][f][e][d], e = i*32+j.
// Reads are lane-coalesced along u (stride 1). Writes are float4 but scattered
// (one 64B line per 16B written) -> ~32MB effective write, ~6us. Fine for now.
// ---------------------------------------------------------------------------
__global__ __launch_bounds__(256) void tr_k(const float* __restrict__ K,
                                            float* __restrict__ K2) {
    int t = blockIdx.x * 256 + threadIdx.x;   // 524288 threads = 64u*8f*1024e
    int u = t & 63;
    int f = (t >> 6) & 7;
    int e = t >> 9;                           // 0..1023
    int base = e * 512 + f * 64 + u;          // + d*524288
    f32x4 v;
    v[0] = K[base];
    v[1] = K[base + 524288];
    v[2] = K[base + 1048576];
    v[3] = K[base + 1572864];
    ((f32x4*)K2)[(u * NF + f) * 1024 + e] = v;
}

// ---------------------------------------------------------------------------
// Main: one wave per (b,u). N = (T_0...T_f)^T kept in C/D regs as 2x2 tiles of
// 16x16. Step: N' = T_f^T @ N via 4x mfma_f32_16x16x32_bf16.
//   A-frag (T_f^T rows I*16..+15): lane(c=lane&15,q=lane>>4) holds
//     T_f[k][I*16+c] for k=8q+j  -> e = k*32 + I*16 + c, dot4 with X[b][f][:].
//   B-frag (N cols J*16..+15): from LDS Nb[n][r] (bf16, row stride 80B:
//     odd multiple of 16 -> conflict-free b128 reads & b64 writes).
//   f=0: B = identity fragments (constants) => N_0 = T_0^T.
// Output: trace = sum of diag of tiles (0,0) and (1,1), wave-reduced.
// ---------------------------------------------------------------------------
template <bool USE_K2>
__global__ __launch_bounds__(256) void tr_main(const float* __restrict__ X,
                                               const float* __restrict__ KK,
                                               float* __restrict__ out) {
    const int tid  = threadIdx.x;
    const int w    = tid >> 6;        // wave in block (4 waves)
    const int lane = tid & 63;
    const int c    = lane & 15;
    const int q    = lane >> 4;
    const int u    = blockIdx.x & 63;             // same u for all 4 waves
    const int b    = ((blockIdx.x >> 6) << 2) + w;

    __shared__ __attribute__((aligned(16))) char lds_raw[4 * 2560];
    char* Nb = lds_raw + w * 2560;    // Nb[n][r]: byte = n*80 + 2*r

    // identity B-frags: I[k][n], n = J*16+c, k = 8q+j
    s16x8 idf0, idf1;
#pragma unroll
    for (int jj = 0; jj < 8; ++jj) {
        idf0[jj] = (short)((8 * q + jj == c) ? 0x3F80 : 0);
        idf1[jj] = (short)((8 * q + jj == 16 + c) ? 0x3F80 : 0);
    }

    f32x4 acc00 = {0,0,0,0}, acc01 = {0,0,0,0}, acc10 = {0,0,0,0}, acc11 = {0,0,0,0};

    const f32x4* Xp = (const f32x4*)(X + b * (NF * ND));  // Xp[f] = X[b][f][0..3]

#pragma unroll
    for (int f = 0; f < NF; ++f) {
        f32x4 x = Xp[f];

        // ---- build A-frags (T_f^T) in fp32, round to bf16 ----
        s16x8 af0, af1;
        if (USE_K2) {
            const f32x4* Kp = (const f32x4*)KK + (((u * NF + f) << 10) + (q << 8) + c);
#pragma unroll
            for (int I = 0; I < 2; ++I) {
                const f32x4* p = Kp + (I << 4);
#pragma unroll
                for (int j = 0; j < 8; ++j) {
                    f32x4 kv = p[j << 5];   // e = 256q + 32j + 16I + c
                    float t = x[0]*kv[0] + x[1]*kv[1] + x[2]*kv[2] + x[3]*kv[3];
                    unsigned short bb = to_bf16_bits(t);
                    if (I == 0) af0[j] = (short)bb; else af1[j] = (short)bb;
                }
            }
        } else {
            // fallback: read original K layout (uncoalesced but correct)
#pragma unroll
            for (int I = 0; I < 2; ++I) {
#pragma unroll
                for (int j = 0; j < 8; ++j) {
                    int e = (q << 8) + (j << 5) + (I << 4) + c;
                    int base = (e << 9) + (f << 6) + u;
                    float t = x[0] * KK[base]
                            + x[1] * KK[base + 524288]
                            + x[2] * KK[base + 1048576]
                            + x[3] * KK[base + 1572864];
                    unsigned short bb = to_bf16_bits(t);
                    if (I == 0) af0[j] = (short)bb; else af1[j] = (short)bb;
                }
            }
        }

        // ---- B-frags ----
        s16x8 bf0, bf1;
        if (f == 0) {
            bf0 = idf0; bf1 = idf1;
        } else {
            bf0 = *(const s16x8*)(Nb + c * 80 + (q << 4));
            bf1 = *(const s16x8*)(Nb + (16 + c) * 80 + (q << 4));
        }

        // ---- 4 MFMAs: N' tiles ----
        const f32x4 z = {0.f, 0.f, 0.f, 0.f};
        acc00 = __builtin_amdgcn_mfma_f32_16x16x32_bf16(af0, bf0, z, 0, 0, 0);
        acc01 = __builtin_amdgcn_mfma_f32_16x16x32_bf16(af0, bf1, z, 0, 0, 0);
        acc10 = __builtin_amdgcn_mfma_f32_16x16x32_bf16(af1, bf0, z, 0, 0, 0);
        acc11 = __builtin_amdgcn_mfma_f32_16x16x32_bf16(af1, bf1, z, 0, 0, 0);

        // ---- write N' to LDS as bf16 (except final f) ----
        if (f < NF - 1) {
#pragma unroll
            for (int I = 0; I < 2; ++I) {
#pragma unroll
                for (int J = 0; J < 2; ++J) {
                    f32x4 a = (I == 0) ? (J == 0 ? acc00 : acc01)
                                       : (J == 0 ? acc10 : acc11);
                    unsigned int d0 = (unsigned int)to_bf16_bits(a[0])
                                    | ((unsigned int)to_bf16_bits(a[1]) << 16);
                    unsigned int d1 = (unsigned int)to_bf16_bits(a[2])
                                    | ((unsigned int)to_bf16_bits(a[3]) << 16);
                    uint2 val; val.x = d0; val.y = d1;
                    // row r = I*16 + 4q (+ri), col n = J*16 + c
                    *(uint2*)(Nb + (J * 16 + c) * 80 + I * 32 + (q << 3)) = val;
                }
            }
        }
        __syncthreads();  // keeps 4 waves phase-locked (L1 K2 reuse) + LDS fence
    }

    // ---- trace: diag of tiles (0,0) and (1,1): local row 4q+ri == col c ----
    float s = 0.f;
    if ((c >> 2) == q) {
        int ri = c & 3;
        s = acc00[ri] + acc11[ri];
    }
#pragma unroll
    for (int off = 32; off > 0; off >>= 1) s += __shfl_down(s, off, 64);
    if (lane == 0) out[b * NU + u] = s;
}

extern "C" void kernel_launch(void* const* d_in, const int* in_sizes, int n_in,
                              void* d_out, int out_size, void* d_ws, size_t ws_size,
                              hipStream_t stream) {
    const float* X = (const float*)d_in[0];   // [512][8][4]
    const float* K = (const float*)d_in[1];   // [4][32][32][8][64]
    float* out = (float*)d_out;               // [512][64]

    if (ws_size >= (size_t)8 * 1024 * 1024) {
        float* K2 = (float*)d_ws;             // [64][8][1024][4]
        hipLaunchKernelGGL(tr_k, dim3(2048), dim3(256), 0, stream, K, K2);
        hipLaunchKernelGGL((tr_main<true>), dim3(8192), dim3(256), 0, stream,
                           X, K2, out);
    } else {
        hipLaunchKernelGGL((tr_main<false>), dim3(8192), dim3(256), 0, stream,
                           X, K, out);
    }
}

// Round 3
// 175.373 us; speedup vs baseline: 1.1047x; 1.1047x over previous
//
#include <hip/hip_runtime.h>
#include <hip/hip_bf16.h>

// Problem constants (fixed by reference): B=512, F=8, D=4, R=32, U=64
#define NB 512
#define NF 8
#define ND 4
#define NR 32
#define NU 64
#define G  8   // batches (b) per wave

typedef float f32x4 __attribute__((ext_vector_type(4)));
typedef float f32x2 __attribute__((ext_vector_type(2)));
typedef short s16x8 __attribute__((ext_vector_type(8)));

// ---- packed fp32 math (exists since gfx90a; standard hand-asm idiom) ------
__device__ inline f32x2 pk_mul(f32x2 a, f32x2 b) {
    f32x2 d;
    asm("v_pk_mul_f32 %0, %1, %2" : "=v"(d) : "v"(a), "v"(b));
    return d;
}
__device__ inline f32x2 pk_fma(f32x2 a, f32x2 b, f32x2 c) {
    f32x2 d;
    asm("v_pk_fma_f32 %0, %1, %2, %3" : "=v"(d) : "v"(a), "v"(b), "v"(c));
    return d;
}
// PROVEN (rounds 0-1) branchless RNE fp32->bf16, packed per pair: 8 VALU ops.
__device__ inline unsigned cvt_pk_bf16(float lo, float hi) {
    unsigned ul = __float_as_uint(lo);
    unsigned uh = __float_as_uint(hi);
    unsigned rl = (ul + 0x7FFFu + ((ul >> 16) & 1u)) >> 16;
    unsigned rh = (uh + 0x7FFFu + ((uh >> 16) & 1u)) & 0xFFFF0000u;
    return rh | rl;
}

// ---------------------------------------------------------------------------
// Pre-pass: K[d][i][j][f][u] -> K3, pair-interleaved for v_pk_fma:
//   K3 float index = (u*8+f)*4096 + (q*4+jp)*256 + ((I*16+c)*4 + d)*2 + par
// where e = 256q + 64jp + 32par + 16I + c  (e = i*32+j). A lane (c,q) then
// reads its (jp,I) slice as two float4s: {d0e0,d0e1,d1e0,d1e1},{d2...,d3...}.
// LDS-tiled transpose: coalesced 16B reads (along u), 128B-run writes.
// Grid: 256 blocks = f(8) x q(4) x jp(4) x uhalf(2); 256 threads.
// ---------------------------------------------------------------------------
__global__ __launch_bounds__(256) void tr_k3(const float* __restrict__ K,
                                             float* __restrict__ K3) {
    __shared__ float lds[256 * 36];   // rows (d*64+s) x 32 u, pad to 36
    const int t   = threadIdx.x;
    const int bid = blockIdx.x;
    const int uh = bid & 1, jp = (bid >> 1) & 3, q = (bid >> 3) & 3, f = bid >> 5;
    const int u0 = uh * 32;

    {   // read phase: rows r = d*64 + s, 32 floats of u each
        const int rr = t >> 3, col4 = (t & 7) * 4;
#pragma unroll
        for (int i = 0; i < 8; ++i) {
            int r = i * 32 + rr;              // 0..255
            int d = r >> 6, s = r & 63;
            int e = q * 256 + jp * 64 + s;
            f32x4 v = *(const f32x4*)(K + ((size_t)((d << 10) + e) << 9)
                                        + (f << 6) + u0 + col4);
            *(f32x4*)(lds + r * 36 + col4) = v;
        }
    }
    __syncthreads();
    {   // write phase: per u_l, 256 consecutive floats; 8 lanes x 16B = 128B runs
        const int u_l = t >> 3, lane8 = t & 7;
        float* dst = K3 + ((size_t)((u0 + u_l) * 8 + f) << 12) + (q * 4 + jp) * 256;
#pragma unroll
        for (int g2 = 0; g2 < 8; ++g2) {
            int idx4 = lane8 + g2 * 8;        // 0..63
            int dh = idx4 & 1, Ic = idx4 >> 1;  // Ic = I*16+c in 0..31
            int d0 = dh * 2;
            f32x4 v;
            v[0] = lds[(d0 * 64 + 0  + Ic) * 36 + u_l];   // (d0, par0)
            v[1] = lds[(d0 * 64 + 32 + Ic) * 36 + u_l];   // (d0, par1)
            v[2] = lds[((d0 + 1) * 64 + 0  + Ic) * 36 + u_l];
            v[3] = lds[((d0 + 1) * 64 + 32 + Ic) * 36 + u_l];
            *(f32x4*)(dst + idx4 * 4) = v;
        }
    }
}

// ---------------------------------------------------------------------------
// Main: one wave handles 8 b's for one u. Per f: load the 16 shared K3
// vectors once, then per b: dot4 via v_pk_fma (2 e's at a time), cvt to
// bf16 A-frags (T_f^T), chain step N' = T_f^T * N via mfma_16x16x32_bf16
// (B-frags from wave-private LDS N-buffer; identity at f=0).
// NO __syncthreads: N-buffers are wave-private and the DS pipe processes a
// wave's LDS ops in order. BUT the compiler must not hoist next-f ds_reads
// above this-f ds_writes (uint2 stores vs s16x8 loads look no-alias to
// TBAA) -> asm volatile memory fence at the end of each f iteration.
// This was the round-2 NaN: no fence, reads hoisted, uninit LDS -> NaN.
// N-buffer layout (per b, 2048B): slot (p, n), p = row>>3, n = col:
//   slot byte = (p*32 + n)*16; within slot, bf16 t -> row 8p + t.
//   Write: uint2 at slot(2I + (q>>1), 16J + c) + 8*(q&1); read: b128 at
//   slot(q, c) / slot(q, 16+c). Max 2-way bank aliasing (free per m136).
// ---------------------------------------------------------------------------
__global__ __launch_bounds__(128, 2) void tr_main3(const float* __restrict__ X,
                                                   const float* __restrict__ K3,
                                                   float* __restrict__ out) {
    const int tid  = threadIdx.x;
    const int w    = tid >> 6;          // 2 waves/block
    const int lane = tid & 63;
    const int c    = lane & 15;
    const int q    = lane >> 4;
    const int u    = blockIdx.x & 63;                 // same-u blocks -> same XCD
    const int b0   = (((blockIdx.x >> 6) << 1) + w) * G;

    __shared__ __attribute__((aligned(16))) char lds[2 * G * 2048];
    char* Nb0 = lds + w * (G * 2048);

    // identity B-frags for f=0: B[k=8q+j][n=c(+16)]
    s16x8 idf0, idf1;
#pragma unroll
    for (int jj = 0; jj < 8; ++jj) {
        idf0[jj] = (short)((8 * q + jj == c) ? 0x3F80 : 0);
        idf1[jj] = (short)((8 * q + jj == 16 + c) ? 0x3F80 : 0);
    }

    const float* Kt = K3 + ((size_t)u << 15) + (q << 10) + (c << 3);
    const f32x4 z = {0.f, 0.f, 0.f, 0.f};

    for (int f = 0; f < NF; ++f) {
        const float* Kf = Kt + (f << 12);
        // shared staging: 16 x b128, reused by all 8 b's
        f32x4 Lv[8], Lw[8];
#pragma unroll
        for (int jp = 0; jp < 4; ++jp)
#pragma unroll
            for (int I = 0; I < 2; ++I) {
                const float* p = Kf + (jp << 8) + (I << 7);
                Lv[(jp << 1) | I] = *(const f32x4*)p;        // d0,d1 pairs
                Lw[(jp << 1) | I] = *(const f32x4*)(p + 4);  // d2,d3 pairs
            }

#pragma unroll
        for (int g = 0; g < G; ++g) {
            char* nb = Nb0 + (g << 11);

            // B-frags early (hide ds_read latency under the dot4 burst)
            s16x8 bf0, bf1;
            if (f == 0) { bf0 = idf0; bf1 = idf1; }
            else {
                bf0 = *(const s16x8*)(nb + (((q << 5) | c) << 4));
                bf1 = *(const s16x8*)(nb + (((q << 5) | c) << 4) + 256);
            }

            // x (wave-uniform -> scalar loads)
            const f32x4 xv = *(const f32x4*)(X + ((b0 + g) << 5) + (f << 2));
            f32x2 xp0 = {xv[0], xv[0]}, xp1 = {xv[1], xv[1]};
            f32x2 xp2 = {xv[2], xv[2]}, xp3 = {xv[3], xv[3]};

            // A-frags: T^T rows, two e's per pk chain, pair-packed cvt
            union { unsigned u4[4]; s16x8 v; } A0, A1;
#pragma unroll
            for (int jp = 0; jp < 4; ++jp)
#pragma unroll
                for (int I = 0; I < 2; ++I) {
                    f32x4 a = Lv[(jp << 1) | I], b = Lw[(jp << 1) | I];
                    f32x2 p0 = {a[0], a[1]}, p1 = {a[2], a[3]};
                    f32x2 p2 = {b[0], b[1]}, p3 = {b[2], b[3]};
                    f32x2 tv = pk_mul(p0, xp0);
                    tv = pk_fma(p1, xp1, tv);
                    tv = pk_fma(p2, xp2, tv);
                    tv = pk_fma(p3, xp3, tv);
                    unsigned pk = cvt_pk_bf16(tv[0], tv[1]);
                    if (I == 0) A0.u4[jp] = pk; else A1.u4[jp] = pk;
                }

            if (f < NF - 1) {
                f32x4 c00 = __builtin_amdgcn_mfma_f32_16x16x32_bf16(A0.v, bf0, z, 0, 0, 0);
                f32x4 c01 = __builtin_amdgcn_mfma_f32_16x16x32_bf16(A0.v, bf1, z, 0, 0, 0);
                f32x4 c10 = __builtin_amdgcn_mfma_f32_16x16x32_bf16(A1.v, bf0, z, 0, 0, 0);
                f32x4 c11 = __builtin_amdgcn_mfma_f32_16x16x32_bf16(A1.v, bf1, z, 0, 0, 0);
                // writeback N' (bf16) for next f
#pragma unroll
                for (int I = 0; I < 2; ++I)
#pragma unroll
                    for (int J = 0; J < 2; ++J) {
                        f32x4 a = (I == 0) ? (J == 0 ? c00 : c01)
                                           : (J == 0 ? c10 : c11);
                        unsigned lo = cvt_pk_bf16(a[0], a[1]);
                        unsigned hi = cvt_pk_bf16(a[2], a[3]);
                        uint2 val; val.x = lo; val.y = hi;
                        // slot(p = 2I + (q>>1), n = 16J + c), byte +8*(q&1)
                        *(uint2*)(nb + (((((I << 1) | (q >> 1)) << 5) | (J << 4) | c) << 4)
                                     + ((q & 1) << 3)) = val;
                    }
            } else {
                // last step: only diagonal tiles feed the trace
                f32x4 c00 = __builtin_amdgcn_mfma_f32_16x16x32_bf16(A0.v, bf0, z, 0, 0, 0);
                f32x4 c11 = __builtin_amdgcn_mfma_f32_16x16x32_bf16(A1.v, bf1, z, 0, 0, 0);
                f32x4 t4 = c00 + c11;
                int ri = c & 3;
                float s = (ri == 0) ? t4[0] : (ri == 1) ? t4[1]
                        : (ri == 2) ? t4[2] : t4[3];
                s = ((c >> 2) == q) ? s : 0.f;
#pragma unroll
                for (int m = 32; m >= 1; m >>= 1) s += __shfl_xor(s, m, 64);
                if (lane == 0) out[((b0 + g) << 6) + u] = s;
            }
        }
        // Compiler memory fence: this-f LDS writes must precede next-f LDS
        // reads in program order (HW DS pipe is in-order per wave; only the
        // compiler could break it). Zero instructions emitted.
        asm volatile("" ::: "memory");
    }
}

extern "C" void kernel_launch(void* const* d_in, const int* in_sizes, int n_in,
                              void* d_out, int out_size, void* d_ws, size_t ws_size,
                              hipStream_t stream) {
    (void)in_sizes; (void)n_in; (void)out_size; (void)ws_size;
    const float* X = (const float*)d_in[0];   // [512][8][4]
    const float* K = (const float*)d_in[1];   // [4][32][32][8][64]
    float* out = (float*)d_out;               // [512][64]
    float* K3 = (float*)d_ws;                 // 8 MB, pair-interleaved

    hipLaunchKernelGGL(tr_k3, dim3(256), dim3(256), 0, stream, K, K3);
    hipLaunchKernelGGL(tr_main3, dim3(2048), dim3(128), 0, stream, X, K3, out);
}

// Round 4
// 128.156 us; speedup vs baseline: 1.5117x; 1.3684x over previous
//
#include <hip/hip_runtime.h>
#include <hip/hip_bf16.h>

// Problem constants (fixed by reference): B=512, F=8, D=4, R=32, U=64
#define NB 512
#define NF 8
#define ND 4
#define NR 32
#define NU 64
#define G  4   // batches (b) per wave

typedef float f32x4 __attribute__((ext_vector_type(4)));
typedef float f32x2 __attribute__((ext_vector_type(2)));
typedef short s16x8 __attribute__((ext_vector_type(8)));
typedef unsigned u32x4 __attribute__((ext_vector_type(4)));

// ---- packed fp32 math (exists since gfx90a; standard hand-asm idiom) ------
__device__ inline f32x2 pk_mul(f32x2 a, f32x2 b) {
    f32x2 d;
    asm("v_pk_mul_f32 %0, %1, %2" : "=v"(d) : "v"(a), "v"(b));
    return d;
}
__device__ inline f32x2 pk_fma(f32x2 a, f32x2 b, f32x2 c) {
    f32x2 d;
    asm("v_pk_fma_f32 %0, %1, %2, %3" : "=v"(d) : "v"(a), "v"(b), "v"(c));
    return d;
}
// fp32 pair -> packed bf16, round-half-up (3 VALU: 2 add + 1 perm).
// Differs from RNE only on exact-tie mantissas (prob ~0 for random data);
// R1/R3 absmax was 0.25 with RNE, threshold 0.74 -> safe.
__device__ inline unsigned cvt_pk_rnu(float lo, float hi) {
    unsigned ul = __float_as_uint(lo) + 0x8000u;
    unsigned uh = __float_as_uint(hi) + 0x8000u;
    // result = [uh.b3, uh.b2, ul.b3, ul.b2] = (hi_bf16 << 16) | lo_bf16
    return __builtin_amdgcn_perm(uh, ul, 0x07060302u);
}

// ---------------------------------------------------------------------------
// Pre-pass: K[d][i][j][f][u] -> K3, pair-interleaved for v_pk_fma:
//   K3 float index = (u*8+f)*4096 + (q*4+jp)*256 + ((I*16+c)*4 + d)*2 + par
// where e = 256q + 64jp + 32par + 16I + c  (e = i*32+j). A lane (c,q) then
// reads its (jp,I) slice as two float4s: {d0e0,d0e1,d1e0,d1e1},{d2...,d3...}.
// LDS-tiled transpose: coalesced 16B reads (along u), 128B-run writes.
// Grid: 256 blocks = f(8) x q(4) x jp(4) x uhalf(2); 256 threads. ~4 us.
// ---------------------------------------------------------------------------
__global__ __launch_bounds__(256) void tr_k3(const float* __restrict__ K,
                                             float* __restrict__ K3) {
    __shared__ float lds[256 * 36];   // rows (d*64+s) x 32 u, pad to 36
    const int t   = threadIdx.x;
    const int bid = blockIdx.x;
    const int uh = bid & 1, jp = (bid >> 1) & 3, q = (bid >> 3) & 3, f = bid >> 5;
    const int u0 = uh * 32;

    {   // read phase: rows r = d*64 + s, 32 floats of u each
        const int rr = t >> 3, col4 = (t & 7) * 4;
#pragma unroll
        for (int i = 0; i < 8; ++i) {
            int r = i * 32 + rr;              // 0..255
            int d = r >> 6, s = r & 63;
            int e = q * 256 + jp * 64 + s;
            f32x4 v = *(const f32x4*)(K + ((size_t)((d << 10) + e) << 9)
                                        + (f << 6) + u0 + col4);
            *(f32x4*)(lds + r * 36 + col4) = v;
        }
    }
    __syncthreads();
    {   // write phase: per u_l, 256 consecutive floats; 8 lanes x 16B = 128B runs
        const int u_l = t >> 3, lane8 = t & 7;
        float* dst = K3 + ((size_t)((u0 + u_l) * 8 + f) << 12) + (q * 4 + jp) * 256;
#pragma unroll
        for (int g2 = 0; g2 < 8; ++g2) {
            int idx4 = lane8 + g2 * 8;        // 0..63
            int dh = idx4 & 1, Ic = idx4 >> 1;  // Ic = I*16+c in 0..31
            int d0 = dh * 2;
            f32x4 v;
            v[0] = lds[(d0 * 64 + 0  + Ic) * 36 + u_l];   // (d0, par0)
            v[1] = lds[(d0 * 64 + 32 + Ic) * 36 + u_l];   // (d0, par1)
            v[2] = lds[((d0 + 1) * 64 + 0  + Ic) * 36 + u_l];
            v[3] = lds[((d0 + 1) * 64 + 32 + Ic) * 36 + u_l];
            *(f32x4*)(dst + idx4 * 4) = v;
        }
    }
}

// ---------------------------------------------------------------------------
// Main: one wave handles G=4 b's for one u. Per f: load the 16 shared K3
// vectors once, then per b: dot4 via v_pk_fma (2 e's at a time), 3-op cvt to
// bf16 A-frags (T_f^T), chain step N' = T_f^T * N via mfma_16x16x32_bf16
// (B-frags from wave-private LDS N-buffer; identity at f=0).
// NO __syncthreads: N-buffers are wave-private; DS pipe is in-order per wave.
// asm memory fence at end of each f stops the compiler hoisting next-f
// ds_reads above this-f ds_writes (the round-2 NaN).
// N-buffer layout (per b, 2048B): slot (p, n), p = row>>3, n = col:
//   slot byte = (p*32 + n)*16; within slot, bf16 t -> row 8p + t.
//   Write: uint2 at slot(2I + (q>>1), 16J + c) + 8*(q&1); read: b128 at
//   slot(q, c) / slot(q, 16+c). Max 2-way bank aliasing (free per m136).
// Occupancy plan: LDS 16KB/block (8 blocks/CU), launch_bounds(128,4) caps
// VGPR at 128 -> 16 waves/CU target (R3 had ~5: latency-bound).
// Block order u-major: same-u blocks dispatch-adjacent -> per-XCD L2
// working set ~1MB (vs 8MB interleaved in R3).
// ---------------------------------------------------------------------------
__global__ __launch_bounds__(128, 4) void tr_main4(const float* __restrict__ X,
                                                   const float* __restrict__ K3,
                                                   float* __restrict__ out) {
    const int tid  = threadIdx.x;
    const int w    = tid >> 6;          // 2 waves/block
    const int lane = tid & 63;
    const int c    = lane & 15;
    const int q    = lane >> 4;
    const int u      = blockIdx.x >> 6;               // u-major
    const int bgroup = blockIdx.x & 63;
    const int b0     = ((bgroup << 1) + w) * G;

    __shared__ __attribute__((aligned(16))) char lds[2 * G * 2048];
    char* Nb0 = lds + w * (G * 2048);

    // identity B-frags for f=0: B[k=8q+j][n=c(+16)]
    s16x8 idf0, idf1;
#pragma unroll
    for (int jj = 0; jj < 8; ++jj) {
        idf0[jj] = (short)((8 * q + jj == c) ? 0x3F80 : 0);
        idf1[jj] = (short)((8 * q + jj == 16 + c) ? 0x3F80 : 0);
    }

    const float* Kt = K3 + ((size_t)u << 15) + (q << 10) + (c << 3);
    const f32x4 z = {0.f, 0.f, 0.f, 0.f};

    for (int f = 0; f < NF; ++f) {
        const float* Kf = Kt + (f << 12);
        // shared staging: 16 x b128, reused by all G b's
        f32x4 Lv[8], Lw[8];
#pragma unroll
        for (int jp = 0; jp < 4; ++jp)
#pragma unroll
            for (int I = 0; I < 2; ++I) {
                const float* p = Kf + (jp << 8) + (I << 7);
                Lv[(jp << 1) | I] = *(const f32x4*)p;        // d0,d1 pairs
                Lw[(jp << 1) | I] = *(const f32x4*)(p + 4);  // d2,d3 pairs
            }

#pragma unroll
        for (int g = 0; g < G; ++g) {
            char* nb = Nb0 + (g << 11);

            // B-frags early (hide ds_read latency under the dot4 burst)
            s16x8 bf0, bf1;
            if (f == 0) { bf0 = idf0; bf1 = idf1; }
            else {
                bf0 = *(const s16x8*)(nb + (((q << 5) | c) << 4));
                bf1 = *(const s16x8*)(nb + (((q << 5) | c) << 4) + 256);
            }

            // x (L1-hot; 64KB total X)
            const f32x4 xv = *(const f32x4*)(X + ((b0 + g) << 5) + (f << 2));
            f32x2 xp0 = {xv[0], xv[0]}, xp1 = {xv[1], xv[1]};
            f32x2 xp2 = {xv[2], xv[2]}, xp3 = {xv[3], xv[3]};

            // A-frags: T^T rows, two e's per pk chain, 3-op packed cvt
            u32x4 A0u, A1u;
#pragma unroll
            for (int jp = 0; jp < 4; ++jp)
#pragma unroll
                for (int I = 0; I < 2; ++I) {
                    f32x4 a = Lv[(jp << 1) | I], b = Lw[(jp << 1) | I];
                    f32x2 p0 = {a[0], a[1]}, p1 = {a[2], a[3]};
                    f32x2 p2 = {b[0], b[1]}, p3 = {b[2], b[3]};
                    f32x2 tv = pk_mul(p0, xp0);
                    tv = pk_fma(p1, xp1, tv);
                    tv = pk_fma(p2, xp2, tv);
                    tv = pk_fma(p3, xp3, tv);
                    unsigned pk = cvt_pk_rnu(tv[0], tv[1]);
                    if (I == 0) A0u[jp] = pk; else A1u[jp] = pk;
                }
            s16x8 A0 = __builtin_bit_cast(s16x8, A0u);
            s16x8 A1 = __builtin_bit_cast(s16x8, A1u);

            if (f < NF - 1) {
                f32x4 c00 = __builtin_amdgcn_mfma_f32_16x16x32_bf16(A0, bf0, z, 0, 0, 0);
                f32x4 c01 = __builtin_amdgcn_mfma_f32_16x16x32_bf16(A0, bf1, z, 0, 0, 0);
                f32x4 c10 = __builtin_amdgcn_mfma_f32_16x16x32_bf16(A1, bf0, z, 0, 0, 0);
                f32x4 c11 = __builtin_amdgcn_mfma_f32_16x16x32_bf16(A1, bf1, z, 0, 0, 0);
                // writeback N' (bf16) for next f
#pragma unroll
                for (int I = 0; I < 2; ++I)
#pragma unroll
                    for (int J = 0; J < 2; ++J) {
                        f32x4 a = (I == 0) ? (J == 0 ? c00 : c01)
                                           : (J == 0 ? c10 : c11);
                        unsigned lo = cvt_pk_rnu(a[0], a[1]);
                        unsigned hi = cvt_pk_rnu(a[2], a[3]);
                        uint2 val; val.x = lo; val.y = hi;
                        // slot(p = 2I + (q>>1), n = 16J + c), byte +8*(q&1)
                        *(uint2*)(nb + (((((I << 1) | (q >> 1)) << 5) | (J << 4) | c) << 4)
                                     + ((q & 1) << 3)) = val;
                    }
            } else {
                // last step: only diagonal tiles feed the trace
                f32x4 c00 = __builtin_amdgcn_mfma_f32_16x16x32_bf16(A0, bf0, z, 0, 0, 0);
                f32x4 c11 = __builtin_amdgcn_mfma_f32_16x16x32_bf16(A1, bf1, z, 0, 0, 0);
                f32x4 t4 = c00 + c11;
                int ri = c & 3;
                float s = (ri == 0) ? t4[0] : (ri == 1) ? t4[1]
                        : (ri == 2) ? t4[2] : t4[3];
                s = ((c >> 2) == q) ? s : 0.f;
#pragma unroll
                for (int m = 32; m >= 1; m >>= 1) s += __shfl_xor(s, m, 64);
                if (lane == 0) out[((b0 + g) << 6) + u] = s;
            }
        }
        // Compiler memory fence: this-f LDS writes must precede next-f LDS
        // reads in program order (HW DS pipe is in-order per wave; only the
        // compiler could break it). Zero instructions emitted.
        asm volatile("" ::: "memory");
    }
}

extern "C" void kernel_launch(void* const* d_in, const int* in_sizes, int n_in,
                              void* d_out, int out_size, void* d_ws, size_t ws_size,
                              hipStream_t stream) {
    (void)in_sizes; (void)n_in; (void)out_size; (void)ws_size;
    const float* X = (const float*)d_in[0];   // [512][8][4]
    const float* K = (const float*)d_in[1];   // [4][32][32][8][64]
    float* out = (float*)d_out;               // [512][64]
    float* K3 = (float*)d_ws;                 // 8 MB, pair-interleaved

    hipLaunchKernelGGL(tr_k3, dim3(256), dim3(256), 0, stream, K, K3);
    hipLaunchKernelGGL(tr_main4, dim3(4096), dim3(128), 0, stream, X, K3, out);
}

// Round 7
// 123.914 us; speedup vs baseline: 1.5634x; 1.0342x over previous
//
#include <hip/hip_runtime.h>
#include <hip/hip_bf16.h>

// Problem constants (fixed by reference): B=512, F=8, D=4, R=32, U=64
#define NB 512
#define NF 8
#define ND 4
#define NR 32
#define NU 64
#define G  4   // batches (b) per wave

typedef float f32x4 __attribute__((ext_vector_type(4)));
typedef float f32x2 __attribute__((ext_vector_type(2)));
typedef short s16x8 __attribute__((ext_vector_type(8)));
typedef unsigned u32x4 __attribute__((ext_vector_type(4)));

// ---- packed fp32 math (exists since gfx90a; standard hand-asm idiom) ------
__device__ inline f32x2 pk_mul(f32x2 a, f32x2 b) {
    f32x2 d;
    asm("v_pk_mul_f32 %0, %1, %2" : "=v"(d) : "v"(a), "v"(b));
    return d;
}
__device__ inline f32x2 pk_fma(f32x2 a, f32x2 b, f32x2 c) {
    f32x2 d;
    asm("v_pk_fma_f32 %0, %1, %2, %3" : "=v"(d) : "v"(a), "v"(b), "v"(c));
    return d;
}

// fp32 pair -> packed bf16 in one 32-bit reg (lo = first arg).
// R5 post-mortem: hand-asm "v_cvt_pk_bf16_f32" produced NaN (wrong operand
// encoding). R6: the BUILTIN version passed its first validation launch
// (absmax 0.25) -> builtin codegen is correct. Fallback: R4-proven 3-op
// software round-half-up (2 add + 1 perm).
__device__ inline unsigned cvt_pk(float lo, float hi) {
#if __has_builtin(__builtin_amdgcn_cvt_pk_bf16_f32)
    auto r = __builtin_amdgcn_cvt_pk_bf16_f32(lo, hi);
    static_assert(sizeof(r) == 4, "cvt_pk_bf16 return must be 32-bit");
    return __builtin_bit_cast(unsigned, r);
#else
    unsigned ul = __float_as_uint(lo) + 0x8000u;
    unsigned uh = __float_as_uint(hi) + 0x8000u;
    // [uh.b3, uh.b2, ul.b3, ul.b2] = (bf16(hi) << 16) | bf16(lo)
    return __builtin_amdgcn_perm(uh, ul, 0x07060302u);
#endif
}

// ---------------------------------------------------------------------------
// Pre-pass: K[d][i][j][f][u] -> K3, pair-interleaved for v_pk_fma:
//   K3 float index = (u*8+f)*4096 + (q*4+jp)*256 + ((I*16+c)*4 + d)*2 + par
// where e = 256q + 64jp + 32par + 16I + c  (e = i*32+j). A lane (c,q) then
// reads its (jp,I) slice as two float4s: {d0e0,d0e1,d1e0,d1e1},{d2...,d3...}.
// LDS-tiled transpose: coalesced 16B reads (along u), 128B-run writes.
// Grid: 256 blocks = f(8) x q(4) x jp(4) x uhalf(2); 256 threads. ~4 us.
// ---------------------------------------------------------------------------
__global__ __launch_bounds__(256) void tr_k3(const float* __restrict__ K,
                                             float* __restrict__ K3) {
    __shared__ float lds[256 * 36];   // rows (d*64+s) x 32 u, pad to 36
    const int t   = threadIdx.x;
    const int bid = blockIdx.x;
    const int uh = bid & 1, jp = (bid >> 1) & 3, q = (bid >> 3) & 3, f = bid >> 5;
    const int u0 = uh * 32;

    {   // read phase: rows r = d*64 + s, 32 floats of u each
        const int rr = t >> 3, col4 = (t & 7) * 4;
#pragma unroll
        for (int i = 0; i < 8; ++i) {
            int r = i * 32 + rr;              // 0..255
            int d = r >> 6, s = r & 63;
            int e = q * 256 + jp * 64 + s;
            f32x4 v = *(const f32x4*)(K + ((size_t)((d << 10) + e) << 9)
                                        + (f << 6) + u0 + col4);
            *(f32x4*)(lds + r * 36 + col4) = v;
        }
    }
    __syncthreads();
    {   // write phase: per u_l, 256 consecutive floats; 8 lanes x 16B = 128B runs
        const int u_l = t >> 3, lane8 = t & 7;
        float* dst = K3 + ((size_t)((u0 + u_l) * 8 + f) << 12) + (q * 4 + jp) * 256;
#pragma unroll
        for (int g2 = 0; g2 < 8; ++g2) {
            int idx4 = lane8 + g2 * 8;        // 0..63
            int dh = idx4 & 1, Ic = idx4 >> 1;  // Ic = I*16+c in 0..31
            int d0 = dh * 2;
            f32x4 v;
            v[0] = lds[(d0 * 64 + 0  + Ic) * 36 + u_l];   // (d0, par0)
            v[1] = lds[(d0 * 64 + 32 + Ic) * 36 + u_l];   // (d0, par1)
            v[2] = lds[((d0 + 1) * 64 + 0  + Ic) * 36 + u_l];
            v[3] = lds[((d0 + 1) * 64 + 32 + Ic) * 36 + u_l];
            *(f32x4*)(dst + idx4 * 4) = v;
        }
    }
}

// ---------------------------------------------------------------------------
// Main: one wave handles G=4 b's for one u. Per f: load the 16 shared K3
// vectors once, then per b: dot4 via v_pk_fma (2 e's at a time), 1-op packed
// cvt to bf16 A-frags (T_f^T), chain step N' = T_f^T * N via
// mfma_16x16x32_bf16 (B-frags from wave-private LDS N-buffer; id at f=0).
// NO __syncthreads: N-buffers are wave-private; DS pipe is in-order per wave.
// asm memory fence at end of each f stops the compiler hoisting next-f
// ds_reads above this-f ds_writes (part of the round-2 NaN).
// N-buffer layout (per b, 2048B): slot (p, n), p = row>>3, n = col:
//   slot byte = (p*32 + n)*16; within slot, bf16 t -> row 8p + t.
//   Write: uint2 at slot(2I + (q>>1), 16J + c) + 8*(q&1); read: b128 at
//   slot(q, c) / slot(q, 16+c). Max 2-way bank aliasing (free per m136).
// Block mapping u-MINOR (R1/R3-proven): u = blk & 63. With round-robin
// block->XCD dispatch, XCD = blk&7 = u&7, so each XCD naturally touches only
// the 8 K3 slabs with u = xcd (mod 8) = 1MB, L2-resident (R3: FETCH 4.4MB).
// The R5/R6 hand-built XCD swizzle is both unnecessary (u-minor gives the
// same locality for free) and correlated with both unexplained failures ->
// dropped on evidence.
// ---------------------------------------------------------------------------
__global__ __launch_bounds__(128, 4) void tr_main7(const float* __restrict__ X,
                                                   const float* __restrict__ K3,
                                                   float* __restrict__ out) {
    const int tid  = threadIdx.x;
    const int w    = tid >> 6;          // 2 waves/block
    const int lane = tid & 63;
    const int c    = lane & 15;
    const int q    = lane >> 4;
    const int u      = blockIdx.x & 63;               // u-minor (R3-proven)
    const int bgroup = blockIdx.x >> 6;               // 0..63
    const int b0     = ((bgroup << 1) + w) * G;

    __shared__ __attribute__((aligned(16))) char lds[2 * G * 2048];
    char* Nb0 = lds + w * (G * 2048);

    // identity B-frags for f=0: B[k=8q+j][n=c(+16)]
    s16x8 idf0, idf1;
#pragma unroll
    for (int jj = 0; jj < 8; ++jj) {
        idf0[jj] = (short)((8 * q + jj == c) ? 0x3F80 : 0);
        idf1[jj] = (short)((8 * q + jj == 16 + c) ? 0x3F80 : 0);
    }

    const float* Kt = K3 + ((size_t)u << 15) + (q << 10) + (c << 3);
    const f32x4 z = {0.f, 0.f, 0.f, 0.f};

    for (int f = 0; f < NF; ++f) {
        const float* Kf = Kt + (f << 12);
        // shared staging: 16 x b128, reused by all G b's
        f32x4 Lv[8], Lw[8];
#pragma unroll
        for (int jp = 0; jp < 4; ++jp)
#pragma unroll
            for (int I = 0; I < 2; ++I) {
                const float* pp = Kf + (jp << 8) + (I << 7);
                Lv[(jp << 1) | I] = *(const f32x4*)pp;        // d0,d1 pairs
                Lw[(jp << 1) | I] = *(const f32x4*)(pp + 4);  // d2,d3 pairs
            }

#pragma unroll
        for (int g = 0; g < G; ++g) {
            char* nb = Nb0 + (g << 11);

            // B-frags early (hide ds_read latency under the dot4 burst)
            s16x8 bf0, bf1;
            if (f == 0) { bf0 = idf0; bf1 = idf1; }
            else {
                bf0 = *(const s16x8*)(nb + (((q << 5) | c) << 4));
                bf1 = *(const s16x8*)(nb + (((q << 5) | c) << 4) + 256);
            }

            // x (L1-hot; 64KB total X)
            const f32x4 xv = *(const f32x4*)(X + ((b0 + g) << 5) + (f << 2));
            f32x2 xp0 = {xv[0], xv[0]}, xp1 = {xv[1], xv[1]};
            f32x2 xp2 = {xv[2], xv[2]}, xp3 = {xv[3], xv[3]};

            // A-frags: T^T rows, two e's per pk chain, packed cvt
            u32x4 A0u, A1u;
#pragma unroll
            for (int jp = 0; jp < 4; ++jp)
#pragma unroll
                for (int I = 0; I < 2; ++I) {
                    f32x4 a = Lv[(jp << 1) | I], b = Lw[(jp << 1) | I];
                    f32x2 p0 = {a[0], a[1]}, p1 = {a[2], a[3]};
                    f32x2 p2 = {b[0], b[1]}, p3 = {b[2], b[3]};
                    f32x2 tv = pk_mul(p0, xp0);
                    tv = pk_fma(p1, xp1, tv);
                    tv = pk_fma(p2, xp2, tv);
                    tv = pk_fma(p3, xp3, tv);
                    unsigned pk = cvt_pk(tv[0], tv[1]);
                    if (I == 0) A0u[jp] = pk; else A1u[jp] = pk;
                }
            s16x8 A0 = __builtin_bit_cast(s16x8, A0u);
            s16x8 A1 = __builtin_bit_cast(s16x8, A1u);

            if (f < NF - 1) {
                f32x4 c00 = __builtin_amdgcn_mfma_f32_16x16x32_bf16(A0, bf0, z, 0, 0, 0);
                f32x4 c01 = __builtin_amdgcn_mfma_f32_16x16x32_bf16(A0, bf1, z, 0, 0, 0);
                f32x4 c10 = __builtin_amdgcn_mfma_f32_16x16x32_bf16(A1, bf0, z, 0, 0, 0);
                f32x4 c11 = __builtin_amdgcn_mfma_f32_16x16x32_bf16(A1, bf1, z, 0, 0, 0);
                // writeback N' (bf16) for next f
#pragma unroll
                for (int I = 0; I < 2; ++I)
#pragma unroll
                    for (int J = 0; J < 2; ++J) {
                        f32x4 a = (I == 0) ? (J == 0 ? c00 : c01)
                                           : (J == 0 ? c10 : c11);
                        unsigned lo = cvt_pk(a[0], a[1]);
                        unsigned hi = cvt_pk(a[2], a[3]);
                        uint2 val; val.x = lo; val.y = hi;
                        // slot(p = 2I + (q>>1), n = 16J + c), byte +8*(q&1)
                        *(uint2*)(nb + (((((I << 1) | (q >> 1)) << 5) | (J << 4) | c) << 4)
                                     + ((q & 1) << 3)) = val;
                    }
            } else {
                // last step: only diagonal tiles feed the trace
                f32x4 c00 = __builtin_amdgcn_mfma_f32_16x16x32_bf16(A0, bf0, z, 0, 0, 0);
                f32x4 c11 = __builtin_amdgcn_mfma_f32_16x16x32_bf16(A1, bf1, z, 0, 0, 0);
                f32x4 t4 = c00 + c11;
                int ri = c & 3;
                float s = (ri == 0) ? t4[0] : (ri == 1) ? t4[1]
                        : (ri == 2) ? t4[2] : t4[3];
                s = ((c >> 2) == q) ? s : 0.f;
#pragma unroll
                for (int m = 32; m >= 1; m >>= 1) s += __shfl_xor(s, m, 64);
                if (lane == 0) out[((b0 + g) << 6) + u] = s;
            }
        }
        // Compiler memory fence: this-f LDS writes must precede next-f LDS
        // reads in program order (HW DS pipe is in-order per wave; only the
        // compiler could break it). Zero instructions emitted.
        asm volatile("" ::: "memory");
    }
}

extern "C" void kernel_launch(void* const* d_in, const int* in_sizes, int n_in,
                              void* d_out, int out_size, void* d_ws, size_t ws_size,
                              hipStream_t stream) {
    (void)in_sizes; (void)n_in; (void)out_size; (void)ws_size;
    const float* X = (const float*)d_in[0];   // [512][8][4]
    const float* K = (const float*)d_in[1];   // [4][32][32][8][64]
    float* out = (float*)d_out;               // [512][64]
    float* K3 = (float*)d_ws;                 // 8 MB, pair-interleaved

    hipLaunchKernelGGL(tr_k3, dim3(256), dim3(256), 0, stream, K, K3);
    hipLaunchKernelGGL(tr_main7, dim3(4096), dim3(128), 0, stream, X, K3, out);
}